// Round 1
// baseline (3721.226 us; speedup 1.0000x reference)
//
#include <hip/hip_runtime.h>
#include <math.h>

#define BATCH 16
#define IN 128
#define HD 32
#define NN 2048
#define NE 32768
#define SEQ 100

// ---------------- preprocessing ----------------

__global__ void count_deg(const int* __restrict__ src, const int* __restrict__ dst,
                          int* deg_out, int* deg_in) {
    int e = blockIdx.x * blockDim.x + threadIdx.x;
    if (e < NE) {
        atomicAdd(&deg_out[src[e]], 1);
        atomicAdd(&deg_in[dst[e]], 1);
    }
}

// single block of 256 threads; N=2048 -> 8 elements per thread
__global__ void scan_rowptr(const int* __restrict__ deg_in, int* __restrict__ row_ptr) {
    __shared__ int partial[256];
    int t = threadIdx.x;
    int base = t * 8;
    int vals[8];
    int s = 0;
    for (int j = 0; j < 8; j++) { vals[j] = deg_in[base + j]; s += vals[j]; }
    partial[t] = s;
    __syncthreads();
    if (t == 0) {
        int acc = 0;
        for (int i = 0; i < 256; i++) { int v = partial[i]; partial[i] = acc; acc += v; }
        row_ptr[NN] = acc;  // == NE
    }
    __syncthreads();
    int acc = partial[t];
    for (int j = 0; j < 8; j++) { row_ptr[base + j] = acc; acc += vals[j]; }
}

__global__ void scatter_edges(const int* __restrict__ src, const int* __restrict__ dst,
                              const int* __restrict__ deg_out, const int* __restrict__ deg_in,
                              const int* __restrict__ row_ptr, int* __restrict__ cursor,
                              int* __restrict__ col_idx, float* __restrict__ wgt) {
    int e = blockIdx.x * blockDim.x + threadIdx.x;
    if (e < NE) {
        int s = src[e], d = dst[e];
        int pos = row_ptr[d] + atomicAdd(&cursor[d], 1);
        col_idx[pos] = s;
        float doo = (float)max(deg_out[s], 1);
        float dii = (float)max(deg_in[d], 1);
        wgt[pos] = rsqrtf(doo * dii);
    }
}

// xr/xz/xh = x @ W* + b*  -> [B,H] each, time-invariant
__global__ void xgates(const float* __restrict__ x,
                       const float* __restrict__ Wr, const float* __restrict__ br,
                       const float* __restrict__ Wz, const float* __restrict__ bz,
                       const float* __restrict__ Wh, const float* __restrict__ bh,
                       float* __restrict__ xr, float* __restrict__ xz, float* __restrict__ xh) {
    int t = blockIdx.x * blockDim.x + threadIdx.x;
    if (t < BATCH * HD) {
        int b = t / HD, hh = t % HD;
        float ar = br[hh], az = bz[hh], ah = bh[hh];
        const float* xb = x + b * IN;
        for (int i = 0; i < IN; i++) {
            float xv = xb[i];
            ar += xv * Wr[i * HD + hh];
            az += xv * Wz[i * HD + hh];
            ah += xv * Wh[i * HD + hh];
        }
        xr[t] = ar; xz[t] = az; xh[t] = ah;
    }
}

// ---------------- main recurrent step ----------------
// 256 threads = 8 groups of 32 lanes; each group handles one (b,n); lane = h channel.
__global__ void __launch_bounds__(256) step_kernel(
    const float* __restrict__ h_prev, float* __restrict__ h_next,
    const int* __restrict__ row_ptr, const int* __restrict__ col_idx,
    const float* __restrict__ wgt,
    const float* __restrict__ Wg, const float* __restrict__ bg,
    const float* __restrict__ xr, const float* __restrict__ xz, const float* __restrict__ xh,
    float* __restrict__ out, int t_step) {
    __shared__ float wg_s[HD * HD];
    int tid = threadIdx.x;
    for (int i = tid; i < HD * HD; i += 256) wg_s[i] = Wg[i];
    __syncthreads();

    int g = blockIdx.x * 8 + (tid >> 5);
    int l = tid & 31;
    int b = g >> 11;        // g / NN  (NN = 2048)
    int n = g & (NN - 1);

    const float* hb = h_prev + (size_t)b * (NN * HD);
    int start = row_ptr[n], end = row_ptr[n + 1];

    float agg = 0.f;
    for (int e = start; e < end; e++) {
        int c = col_idx[e];
        float ww = wgt[e];
        agg += ww * hb[c * HD + l];
    }

    float conv = bg[l];
#pragma unroll
    for (int k = 0; k < HD; k++) {
        float ak = __shfl(agg, k, 32);
        conv += ak * wg_s[k * HD + l];
    }

    float xrv = xr[b * HD + l], xzv = xz[b * HD + l], xhv = xh[b * HD + l];
    float r = 1.f / (1.f + expf(-(xrv + conv)));
    float z = 1.f / (1.f + expf(-(xzv + conv)));
    float ht = tanhf(xhv + r * conv);
    float hp = hb[n * HD + l];
    float hn = (1.f - z) * hp + z * ht;

    h_next[(size_t)b * (NN * HD) + n * HD + l] = hn;
    out[((size_t)b * SEQ + t_step) * (NN * HD) + (size_t)n * HD + l] = hn;
}

// ---------------- launch ----------------

extern "C" void kernel_launch(void* const* d_in, const int* in_sizes, int n_in,
                              void* d_out, int out_size, void* d_ws, size_t ws_size,
                              hipStream_t stream) {
    const float* x   = (const float*)d_in[0];
    const int*   src = (const int*)d_in[1];
    const int*   dst = (const int*)d_in[2];
    const float* Wr  = (const float*)d_in[3];
    const float* br  = (const float*)d_in[4];
    const float* Wz  = (const float*)d_in[5];
    const float* bz  = (const float*)d_in[6];
    const float* Wh  = (const float*)d_in[7];
    const float* bh  = (const float*)d_in[8];
    const float* Wg  = (const float*)d_in[9];
    const float* bg  = (const float*)d_in[10];
    float* out = (float*)d_out;

    // workspace carve-up (all 4-byte aligned)
    char* ws = (char*)d_ws;
    float* h0 = (float*)ws;            ws += (size_t)BATCH * NN * HD * 4;   // 4 MB
    float* h1 = (float*)ws;            ws += (size_t)BATCH * NN * HD * 4;   // 4 MB
    float* xr = (float*)ws;            ws += BATCH * HD * 4;
    float* xz = (float*)ws;            ws += BATCH * HD * 4;
    float* xh = (float*)ws;            ws += BATCH * HD * 4;
    int* deg_out = (int*)ws;           ws += NN * 4;
    int* deg_in  = (int*)ws;           ws += NN * 4;
    int* cursor  = (int*)ws;           ws += NN * 4;
    int* row_ptr = (int*)ws;           ws += (NN + 1) * 4;
    int* col_idx = (int*)ws;           ws += NE * 4;
    float* wgt   = (float*)ws;         ws += NE * 4;

    // zero initial h and the three counter arrays (deg_out, deg_in, cursor contiguous)
    hipMemsetAsync(h0, 0, (size_t)BATCH * NN * HD * 4, stream);
    hipMemsetAsync(deg_out, 0, 3 * NN * 4, stream);

    count_deg<<<NE / 256, 256, 0, stream>>>(src, dst, deg_out, deg_in);
    scan_rowptr<<<1, 256, 0, stream>>>(deg_in, row_ptr);
    scatter_edges<<<NE / 256, 256, 0, stream>>>(src, dst, deg_out, deg_in, row_ptr,
                                                cursor, col_idx, wgt);
    xgates<<<2, 256, 0, stream>>>(x, Wr, br, Wz, bz, Wh, bh, xr, xz, xh);

    float* hp = h0;
    float* hn = h1;
    for (int t = 0; t < SEQ; t++) {
        step_kernel<<<BATCH * NN / 8, 256, 0, stream>>>(
            hp, hn, row_ptr, col_idx, wgt, Wg, bg, xr, xz, xh, out, t);
        float* tmp = hp; hp = hn; hn = tmp;
    }
}